// Round 1
// baseline (3464.277 us; speedup 1.0000x reference)
//
#include <hip/hip_runtime.h>
#include <hip/hip_bf16.h>

#define NSTEPS 64

typedef __attribute__((ext_vector_type(8))) short bf16x8;
typedef __attribute__((ext_vector_type(4))) float f32x4;

static __device__ __forceinline__ unsigned short f2bf(float v) {
  union { __hip_bfloat16 h; unsigned short u; } cv;
  cv.h = __float2bfloat16(v);
  return cv.u;
}

// ---------------------------------------------------------------------------
// prep: build MFMA A-fragments for W1 (perceive 3x3, 16->128) and W2 (1x1,
// 128->16) in bf16, stored in d_ws after the ping buffer.
//
// A1 frags: [mb=8][kc=5][lane=64][j=8] bf16.  A1[co][k]:
//   co = 16*mb + (lane&15),  k = 32*kc + 8*(lane>>4) + j,
//   k = tap*16 + ci  (tap = dy*3+dx, 9 taps), zero-padded for k >= 144.
// W2 frags at element 20480: [kc2=4][lane=64][j=8].  A2[co2][k2]:
//   co2 = lane&15, k2 = 32*kc2 + 8*(lane>>4) + j.
// ---------------------------------------------------------------------------
__global__ void ca_prep(const float* __restrict__ w1, const float* __restrict__ w2,
                        __hip_bfloat16* __restrict__ fr) {
  int i = blockIdx.x * 256 + threadIdx.x;
  if (i < 20480) {
    int j  = i & 7;
    int l  = (i >> 3) & 63;
    int fi = i >> 9;          // mb*5 + kc
    int kc = fi % 5, mb = fi / 5;
    int co = mb * 16 + (l & 15);
    int k  = kc * 32 + ((l >> 4) << 3) + j;
    float v = 0.0f;
    if (k < 144) {
      int tap = k >> 4, ci = k & 15;
      v = w1[(co * 16 + ci) * 9 + tap];   // w1[co][ci][dy][dx], tap=dy*3+dx
    }
    fr[i] = __float2bfloat16(v);
  } else if (i < 22528) {
    int i2  = i - 20480;
    int j   = i2 & 7;
    int l   = (i2 >> 3) & 63;
    int kc2 = i2 >> 9;
    int k2  = kc2 * 32 + ((l >> 4) << 3) + j;
    fr[i] = __float2bfloat16(w2[(l & 15) * 128 + k2]);
  }
}

// ---------------------------------------------------------------------------
// one CA step.  grid = 512 blocks (b = bid&7 for XCD-L2 locality, 8x8 tiles of
// 32x32), block = 512 threads = 8 waves.
//
// LDS: h tile bf16, layout [half=2][y=34][x=34][8ch] (16B/pixel/half) so a
//      B1 fragment read is one conflict-free ds_read_b128.           36992 B
//      per-wave relu(p) staging: [pix=16][64ch + 8B pad] = 2304 B/wave 18432 B
// total 55424 B (static).
// ---------------------------------------------------------------------------
__launch_bounds__(512, 2)
__global__ void ca_step(const float* __restrict__ hin,
                        float* __restrict__ hout,
                        const __hip_bfloat16* __restrict__ fr) {
  __shared__ __align__(16) char smem[55424];
  const int tid  = threadIdx.x;
  const int lane = tid & 63;
  const int wv   = tid >> 6;
  const int bid  = blockIdx.x;
  const int b    = bid & 7;          // batch -> XCD (round-robin heuristic)
  const int t    = bid >> 3;
  const int ty   = t >> 3, tx = t & 7;
  const int Y0   = ty << 5, X0 = tx << 5;
  const int ib   = b << 20;          // b * 16 * 65536

  // ---- W1 / W2 fragments into registers (global reads, L2-hot) ----
  bf16x8 a1[8][5];
#pragma unroll
  for (int mb = 0; mb < 8; ++mb)
#pragma unroll
    for (int kc = 0; kc < 5; ++kc)
      a1[mb][kc] = *(const bf16x8*)(fr + (((mb * 5 + kc) * 64 + lane) << 3));
  bf16x8 w2f[4];
#pragma unroll
  for (int kc = 0; kc < 4; ++kc)
    w2f[kc] = *(const bf16x8*)(fr + 20480 + ((kc * 64 + lane) << 3));

  // ---- cooperative halo'd tile load: 34x34 pixels x 16 ch, f32 -> bf16 ----
  for (int i = tid; i < 34 * 34; i += 512) {
    int y  = i / 34;
    int x  = i - y * 34;
    int GY = Y0 + y - 1, GX = X0 + x - 1;
    bool inb = ((unsigned)GY < 256u) && ((unsigned)GX < 256u);
    int gof = ib + (GY << 8) + GX;
    unsigned int pk[8];
#pragma unroll
    for (int c = 0; c < 8; ++c) {
      float v0 = inb ? hin[gof + ((2 * c) << 16)] : 0.0f;
      float v1 = inb ? hin[gof + ((2 * c + 1) << 16)] : 0.0f;
      pk[c] = (unsigned int)f2bf(v0) | ((unsigned int)f2bf(v1) << 16);
    }
    uint4 lo = make_uint4(pk[0], pk[1], pk[2], pk[3]);   // ch 0..7  -> half 0
    uint4 hi = make_uint4(pk[4], pk[5], pk[6], pk[7]);   // ch 8..15 -> half 1
    *(uint4*)(smem + i * 16)         = lo;
    *(uint4*)(smem + 18496 + i * 16) = hi;
  }
  __syncthreads();

  // ---- main loop: 8 pixel-blocks (16 consecutive x at one row) per wave ----
  const int pix     = lane & 15;
  const int g       = lane >> 4;
  const int g1b     = g >> 1;                    // tap-select bit
  const int halfoff = (g & 1) ? 18496 : 0;       // ci half
  char* pbase = smem + 36992 + wv * 2304 + pix * 144;

  const f32x4 z4 = {0.0f, 0.0f, 0.0f, 0.0f};

#pragma unroll 1
  for (int it = 0; it < 8; ++it) {
    const int pb = (wv << 3) + it;
    const int y  = pb >> 1;                      // row in tile, 0..31
    const int xl = ((pb & 1) << 4) + pix;        // col in tile, 0..31

    // GEMM1: p[co][pix] = sum_k W1[co][k] * im2col[k][pix], K padded to 160
    f32x4 accp[8];
#pragma unroll
    for (int mb = 0; mb < 8; ++mb) accp[mb] = z4;

#pragma unroll
    for (int kc = 0; kc < 5; ++kc) {
      const int t0  = 2 * kc;
      const int t1  = (2 * kc + 1 > 8) ? 8 : 2 * kc + 1;  // tap 9 is zero-padded in A1
      const int dy  = g1b ? (t1 / 3) : (t0 / 3);
      const int dxo = g1b ? (t1 % 3) : (t0 % 3);
      const bf16x8 b1 =
          *(const bf16x8*)(smem + halfoff + (((y + dy) * 34) + xl + dxo) * 16);
#pragma unroll
      for (int mb = 0; mb < 8; ++mb)
        accp[mb] = __builtin_amdgcn_mfma_f32_16x16x32_bf16(a1[mb][kc], b1,
                                                           accp[mb], 0, 0, 0);
    }

    // GEMM2: dx[co2][pix] = sum_k2 W2[co2][k2] * relu(p)[k2][pix]
    // two half-stages (64 ch each) through the per-wave LDS region
    f32x4 dxa = z4;
#pragma unroll
    for (int half = 0; half < 2; ++half) {
#pragma unroll
      for (int m4 = 0; m4 < 4; ++m4) {
        const int mb = half * 4 + m4;
        unsigned int lo = (unsigned int)f2bf(fmaxf(accp[mb][0], 0.0f)) |
                          ((unsigned int)f2bf(fmaxf(accp[mb][1], 0.0f)) << 16);
        unsigned int hi = (unsigned int)f2bf(fmaxf(accp[mb][2], 0.0f)) |
                          ((unsigned int)f2bf(fmaxf(accp[mb][3], 0.0f)) << 16);
        *(uint2*)(pbase + m4 * 32 + g * 8) = make_uint2(lo, hi);
      }
      asm volatile("s_waitcnt lgkmcnt(0)" ::: "memory");
#pragma unroll
      for (int k2 = 0; k2 < 2; ++k2) {
        const int kc2 = half * 2 + k2;
        const bf16x8 b2 = *(const bf16x8*)(pbase + k2 * 64 + g * 16);
        dxa = __builtin_amdgcn_mfma_f32_16x16x32_bf16(w2f[kc2], b2, dxa, 0, 0, 0);
      }
    }

    // epilogue: h = clamp(h + dx); exact f32 h re-read (L1/L2-hot)
    const int gb = ib + ((Y0 + y) << 8) + X0 + xl;
#pragma unroll
    for (int r = 0; r < 4; ++r) {
      const int co2 = (g << 2) + r;
      const int off = gb + (co2 << 16);
      float v = hin[off] + dxa[r];
      const float lo = (co2 == 0) ? 0.0f : -3.0f;
      const float hi = (co2 == 0) ? 1.0f : 3.0f;
      v = fminf(fmaxf(v, lo), hi);
      hout[off] = v;
    }
  }
}

// ---------------------------------------------------------------------------
extern "C" void kernel_launch(void* const* d_in, const int* in_sizes, int n_in,
                              void* d_out, int out_size, void* d_ws, size_t ws_size,
                              hipStream_t stream) {
  const float* x  = (const float*)d_in[0];
  const float* w1 = (const float*)d_in[1];
  const float* w2 = (const float*)d_in[2];
  float* out  = (float*)d_out;
  float* ping = (float*)d_ws;                                  // 33.5 MB state
  __hip_bfloat16* fr = (__hip_bfloat16*)((char*)d_ws + 33554432);

  ca_prep<<<88, 256, 0, stream>>>(w1, w2, fr);

  for (int s = 0; s < NSTEPS; ++s) {
    const float* in = (s == 0) ? x : ((s & 1) ? ping : out);
    float* o        = (s & 1) ? out : ping;                    // s=63 -> d_out
    ca_step<<<512, 512, 0, stream>>>(in, o, fr);
  }
}

// Round 2
// 3079.476 us; speedup vs baseline: 1.1250x; 1.1250x over previous
//
#include <hip/hip_runtime.h>
#include <hip/hip_bf16.h>

#define NSTEPS 64

typedef __attribute__((ext_vector_type(8))) short bf16x8;
typedef __attribute__((ext_vector_type(4))) float f32x4;

static __device__ __forceinline__ unsigned short f2bf(float v) {
  union { __hip_bfloat16 h; unsigned short u; } cv;
  cv.h = __float2bfloat16(v);
  return cv.u;
}

static __device__ __forceinline__ unsigned int cvtpk_bf16(float lo, float hi) {
  unsigned int d;
  asm("v_cvt_pk_bf16_f32 %0, %1, %2" : "=v"(d) : "v"(lo), "v"(hi));
  return d;
}

// ---------------------------------------------------------------------------
// prep: build MFMA A-fragments for W1 (perceive 3x3, 16->128) and W2 (1x1,
// 128->16) in bf16, stored in d_ws after the ping buffer.
//
// A1 frags: [mb=8][kc=5][lane=64][j=8] bf16.  A1[m][k] with PERMUTED co:
//   co(mb, m) = (mb>>1)*32 + (m>>2)*8 + (mb&1)*4 + (m&3),  m = lane&15,
//   k = 32*kc + 8*(lane>>4) + j,  k = tap*16 + ci (9 taps), zero for k>=144.
// The permutation makes GEMM1's C/D accumulator layout coincide lane-for-lane
// with GEMM2's B-operand layout (k2 = natural channel order), so relu(p) can
// be packed in-register with no LDS staging and no cross-lane traffic.
// W2 frags at element 20480: [kc2=4][lane=64][j=8].  A2[co2][k2]:
//   co2 = lane&15, k2 = 32*kc2 + 8*(lane>>4) + j  (natural order, unchanged).
// ---------------------------------------------------------------------------
__global__ void ca_prep(const float* __restrict__ w1, const float* __restrict__ w2,
                        __hip_bfloat16* __restrict__ fr) {
  int i = blockIdx.x * 256 + threadIdx.x;
  if (i < 20480) {
    int j  = i & 7;
    int l  = (i >> 3) & 63;
    int fi = i >> 9;          // mb*5 + kc
    int kc = fi % 5, mb = fi / 5;
    int m  = l & 15;
    int co = ((mb >> 1) << 5) + ((m >> 2) << 3) + ((mb & 1) << 2) + (m & 3);
    int k  = kc * 32 + ((l >> 4) << 3) + j;
    float v = 0.0f;
    if (k < 144) {
      int tap = k >> 4, ci = k & 15;
      v = w1[(co * 16 + ci) * 9 + tap];   // w1[co][ci][dy][dx], tap=dy*3+dx
    }
    fr[i] = __float2bfloat16(v);
  } else if (i < 22528) {
    int i2  = i - 20480;
    int j   = i2 & 7;
    int l   = (i2 >> 3) & 63;
    int kc2 = i2 >> 9;
    int k2  = kc2 * 32 + ((l >> 4) << 3) + j;
    fr[i] = __float2bfloat16(w2[(l & 15) * 128 + k2]);
  }
}

// ---------------------------------------------------------------------------
// one CA step.  grid = 1024 blocks: b = bid&7 (batch -> XCD), 8x16 tiles of
// 32x16 pixels.  block = 256 threads = 4 waves; each wave does 8 pixel-blocks.
//
// LDS: h tile bf16, [half=2][y=18][x=34][8ch] (16B/pixel/half).  19584 B.
// Weights live in registers (pinned); GEMM2 is fully in-register.
// ---------------------------------------------------------------------------
__launch_bounds__(256, 2)
__global__ void ca_step(const float* __restrict__ hin,
                        float* __restrict__ hout,
                        const __hip_bfloat16* __restrict__ fr) {
  __shared__ __align__(16) char smem[19584];
  const int tid  = threadIdx.x;
  const int lane = tid & 63;
  const int wv   = tid >> 6;          // 0..3
  const int bid  = blockIdx.x;
  const int b    = bid & 7;           // batch -> XCD round-robin
  const int t    = bid >> 3;          // 0..127
  const int ty   = t >> 3;            // 0..15
  const int tx   = t & 7;             // 0..7
  const int Y0   = ty << 4, X0 = tx << 5;
  const int ib   = b << 20;           // b * 16 * 65536

  // ---- W1 / W2 fragments into registers (L2-hot), then PIN them so the
  //      compiler cannot rematerialize the loads inside the main loop ----
  bf16x8 a1[8][5];
#pragma unroll
  for (int mb = 0; mb < 8; ++mb)
#pragma unroll
    for (int kc = 0; kc < 5; ++kc)
      a1[mb][kc] = *(const bf16x8*)(fr + (((mb * 5 + kc) * 64 + lane) << 3));
  bf16x8 w2f[4];
#pragma unroll
  for (int kc = 0; kc < 4; ++kc)
    w2f[kc] = *(const bf16x8*)(fr + 20480 + ((kc * 64 + lane) << 3));
#pragma unroll
  for (int mb = 0; mb < 8; ++mb)
#pragma unroll
    for (int kc = 0; kc < 5; ++kc)
      asm volatile("" : "+v"(a1[mb][kc]));
#pragma unroll
  for (int kc = 0; kc < 4; ++kc)
    asm volatile("" : "+v"(w2f[kc]));

  // ---- cooperative halo'd tile load: 34x18 pixels x 16 ch, f32 -> bf16 ----
  for (int i = tid; i < 34 * 18; i += 256) {
    int y  = i / 34;
    int x  = i - y * 34;
    int GY = Y0 + y - 1, GX = X0 + x - 1;
    bool inb = ((unsigned)GY < 256u) && ((unsigned)GX < 256u);
    int gof = ib + (GY << 8) + GX;
    unsigned int pk[8];
#pragma unroll
    for (int c = 0; c < 8; ++c) {
      float v0 = inb ? hin[gof + ((2 * c) << 16)] : 0.0f;
      float v1 = inb ? hin[gof + ((2 * c + 1) << 16)] : 0.0f;
      pk[c] = (unsigned int)f2bf(v0) | ((unsigned int)f2bf(v1) << 16);
    }
    *(uint4*)(smem + i * 16)        = make_uint4(pk[0], pk[1], pk[2], pk[3]);
    *(uint4*)(smem + 9792 + i * 16) = make_uint4(pk[4], pk[5], pk[6], pk[7]);
  }
  __syncthreads();

  // ---- main loop: 8 pixel-blocks (16 consecutive x in one row) per wave ----
  const int pix     = lane & 15;
  const int g       = lane >> 4;
  const int g1b     = g >> 1;                    // tap-select bit
  const int halfoff = (g & 1) ? 9792 : 0;        // ci half

  const f32x4 z4 = {0.0f, 0.0f, 0.0f, 0.0f};

#pragma unroll 1
  for (int it = 0; it < 8; ++it) {
    const int pb = (wv << 3) + it;
    const int y  = pb >> 1;                      // row in tile, 0..15
    const int xl = ((pb & 1) << 4) + pix;        // col in tile, 0..31

    // epilogue h values: issue early so L1/L2 latency hides under GEMM1
    const int gb = ib + ((Y0 + y) << 8) + X0 + xl;
    float hv[4];
#pragma unroll
    for (int r = 0; r < 4; ++r)
      hv[r] = hin[gb + (((g << 2) + r) << 16)];

    // GEMM1: p[co][pix], K padded to 160.  B-frag = one ds_read_b128.
    const char* base = smem + halfoff + ((y * 34) + xl) * 16;
    f32x4 accp[8];
#pragma unroll
    for (int mb = 0; mb < 8; ++mb) accp[mb] = z4;

#pragma unroll
    for (int kc = 0; kc < 5; ++kc) {
      const int t0   = 2 * kc;
      const int t1   = (2 * kc + 1 > 8) ? 8 : 2 * kc + 1;  // tap 9 zero-padded
      const int off0 = ((t0 / 3) * 34 + (t0 % 3)) * 16;    // compile-time
      const int off1 = ((t1 / 3) * 34 + (t1 % 3)) * 16;
      const bf16x8 b1 = *(const bf16x8*)(base + (g1b ? off1 : off0));
#pragma unroll
      for (int mb = 0; mb < 8; ++mb)
        accp[mb] = __builtin_amdgcn_mfma_f32_16x16x32_bf16(a1[mb][kc], b1,
                                                           accp[mb], 0, 0, 0);
    }

    // GEMM2: dx[co2][pix] = W2 . relu(p) — fully in-register thanks to the
    // co-permutation (accp IS the B-operand layout, k2 in natural order)
    f32x4 dxa = z4;
#pragma unroll
    for (int kc2 = 0; kc2 < 4; ++kc2) {
      const int me = 2 * kc2, mo = 2 * kc2 + 1;
      union { unsigned int u[4]; bf16x8 v; } bb;
      bb.u[0] = cvtpk_bf16(fmaxf(accp[me][0], 0.0f), fmaxf(accp[me][1], 0.0f));
      bb.u[1] = cvtpk_bf16(fmaxf(accp[me][2], 0.0f), fmaxf(accp[me][3], 0.0f));
      bb.u[2] = cvtpk_bf16(fmaxf(accp[mo][0], 0.0f), fmaxf(accp[mo][1], 0.0f));
      bb.u[3] = cvtpk_bf16(fmaxf(accp[mo][2], 0.0f), fmaxf(accp[mo][3], 0.0f));
      dxa = __builtin_amdgcn_mfma_f32_16x16x32_bf16(w2f[kc2], bb.v, dxa, 0, 0, 0);
    }

    // epilogue: h = clamp(h + dx), exact f32 residual
#pragma unroll
    for (int r = 0; r < 4; ++r) {
      const int co2 = (g << 2) + r;
      float v = hv[r] + dxa[r];
      const float lo = (co2 == 0) ? 0.0f : -3.0f;
      const float hi = (co2 == 0) ? 1.0f : 3.0f;
      v = fminf(fmaxf(v, lo), hi);
      hout[gb + (co2 << 16)] = v;
    }
  }
}

// ---------------------------------------------------------------------------
extern "C" void kernel_launch(void* const* d_in, const int* in_sizes, int n_in,
                              void* d_out, int out_size, void* d_ws, size_t ws_size,
                              hipStream_t stream) {
  const float* x  = (const float*)d_in[0];
  const float* w1 = (const float*)d_in[1];
  const float* w2 = (const float*)d_in[2];
  float* out  = (float*)d_out;
  float* ping = (float*)d_ws;                                  // 33.5 MB state
  __hip_bfloat16* fr = (__hip_bfloat16*)((char*)d_ws + 33554432);

  ca_prep<<<88, 256, 0, stream>>>(w1, w2, fr);

  for (int s = 0; s < NSTEPS; ++s) {
    const float* in = (s == 0) ? x : ((s & 1) ? ping : out);
    float* o        = (s & 1) ? out : ping;                    // s=63 -> d_out
    ca_step<<<1024, 256, 0, stream>>>(in, o, fr);
  }
}